// Round 2
// baseline (346.593 us; speedup 1.0000x reference)
//
#include <hip/hip_runtime.h>
#include <hip/hip_bf16.h>

// BitNetAttention: B=2,S=2048,HID=1024,NH=16,HD=64
#define NB 2
#define NS 2048
#define NHID 1024
#define NHEAD 16
#define NHD 64
#define NTOK (NB*NS)        // 4096
#define WELEM (NHID*NHID)   // 1048576

typedef unsigned short u16;
typedef __attribute__((ext_vector_type(4))) float floatx4;
typedef __attribute__((ext_vector_type(8))) __bf16 bf16x8;
typedef __attribute__((ext_vector_type(8))) unsigned short ushort8;

__device__ __forceinline__ u16 f2bf(float f) {
  union { float f; unsigned u; } a; a.f = f;
  unsigned u = a.u;
  unsigned r = (u + 0x7fffu + ((u >> 16) & 1u)) >> 16;  // RNE
  return (u16)r;
}
__device__ __forceinline__ float bf2f(u16 s) {
  union { unsigned u; float f; } a; a.u = ((unsigned)s) << 16;
  return a.f;
}
__device__ __forceinline__ void gload16(const void* g, void* lds) {
  __builtin_amdgcn_global_load_lds(
      (const __attribute__((address_space(1))) unsigned int*)g,
      (__attribute__((address_space(3))) unsigned int*)lds, 16, 0, 0);
}

// ---------------- scale reduction (fp64 for boundary fidelity) --------------
__global__ void k_init(double* sums) { if (threadIdx.x < 4) sums[threadIdx.x] = 0.0; }

__global__ void k_abssum(const float* __restrict__ wq, const float* __restrict__ wk,
                         const float* __restrict__ wv, const float* __restrict__ wo,
                         double* __restrict__ sums) {
  const float* srcs[4] = {wq, wk, wv, wo};
  const float* w = srcs[blockIdx.y];
  int idx = (blockIdx.x * 256 + threadIdx.x) * 16;
  float s = 0.f;
#pragma unroll
  for (int j = 0; j < 4; j++) {
    float4 v = *(const float4*)(w + idx + j * 4);
    s += fabsf(v.x) + fabsf(v.y) + fabsf(v.z) + fabsf(v.w);
  }
#pragma unroll
  for (int off = 32; off; off >>= 1) s += __shfl_down(s, off);
  __shared__ float ps[4];
  if ((threadIdx.x & 63) == 0) ps[threadIdx.x >> 6] = s;
  __syncthreads();
  if (threadIdx.x == 0) atomicAdd(&sums[blockIdx.y], (double)(ps[0] + ps[1] + ps[2] + ps[3]));
}

__global__ void k_quant(const float* __restrict__ wq, const float* __restrict__ wk,
                        const float* __restrict__ wv, const float* __restrict__ wo,
                        const double* __restrict__ sums, u16* __restrict__ wt) {
  const float* srcs[4] = {wq, wk, wv, wo};
  const float* w = srcs[blockIdx.y];
  u16* dst = wt + blockIdx.y * WELEM;
  float s = (float)(sums[blockIdx.y] / (double)WELEM) + 1e-5f;
  int idx = (blockIdx.x * 256 + threadIdx.x) * 4;
  float4 v = *(const float4*)(w + idx);
  float f[4] = {v.x, v.y, v.z, v.w};
  union { u16 ss[4]; uint2 u; } O;
#pragma unroll
  for (int j = 0; j < 4; j++) {
    float q = rintf(f[j] / s);            // round-half-even, matches np.round
    q = fminf(1.f, fmaxf(-1.f, q));
    O.ss[j] = f2bf(q);                    // ternary exact in bf16
  }
  *(uint2*)(dst + idx) = O.u;
}

// ---------------- fp32 -> bf16 hi/lo split ---------------------------------
__global__ void k_split(const float* __restrict__ x, u16* __restrict__ hi, u16* __restrict__ lo) {
  int idx = (blockIdx.x * 256 + threadIdx.x) * 4;
  float4 v = *(const float4*)(x + idx);
  float f[4] = {v.x, v.y, v.z, v.w};
  union { u16 s[4]; uint2 u; } H, L;
#pragma unroll
  for (int j = 0; j < 4; j++) {
    u16 hb = f2bf(f[j]);
    H.s[j] = hb;
    L.s[j] = f2bf(f[j] - bf2f(hb));
  }
  *(uint2*)(hi + idx) = H.u;
  *(uint2*)(lo + idx) = L.u;
}

// ---------------- GEMM: C[m,o] = sum_k (Ahi+Alo)[m,k] * W[o,k] --------------
template <int MODE>
__global__ __launch_bounds__(256) void k_gemm(
    const u16* __restrict__ Ahi, const u16* __restrict__ Alo,
    const u16* __restrict__ Wt, float* __restrict__ outf,
    u16* __restrict__ qh, u16* __restrict__ ql,
    u16* __restrict__ kh, u16* __restrict__ kl,
    u16* __restrict__ vh, u16* __restrict__ vl) {
  __shared__ __attribute__((aligned(16))) u16 At[128 * 32];
  __shared__ __attribute__((aligned(16))) u16 Bt[128 * 32];
  const int tid = threadIdx.x;
  const int wave = tid >> 6, lane = tid & 63;
  const int lr = lane & 15, lh = lane >> 4;
  const int bm = blockIdx.x, bn = blockIdx.y, z = blockIdx.z;
  const u16* W = Wt + (MODE == 0 ? z : 3) * WELEM;
  const int wr = wave >> 1, wc = wave & 1;

  floatx4 acc[4][4];
#pragma unroll
  for (int i = 0; i < 4; i++)
#pragma unroll
    for (int j = 0; j < 4; j++) acc[i][j] = (floatx4){0.f, 0.f, 0.f, 0.f};

  const int e0 = tid * 8;
  const int row0 = e0 >> 5, col0 = e0 & 31;

  for (int kt = 0; kt < 64; ++kt) {  // K_eff = 2048 = [hi | lo]
    const u16* Asrc = (kt < 32) ? Ahi : Alo;
    const int k0 = (kt & 31) * 32;
#pragma unroll
    for (int it = 0; it < 2; ++it) {
      int row = row0 + it * 64;
      gload16(Asrc + (bm * 128 + row) * 1024 + k0 + col0, (char*)At + it * 4096 + wave * 1024);
      gload16(W    + (bn * 128 + row) * 1024 + k0 + col0, (char*)Bt + it * 4096 + wave * 1024);
    }
    __syncthreads();
    bf16x8 af[4], bfr[4];
#pragma unroll
    for (int mi = 0; mi < 4; mi++)
      af[mi] = *(const bf16x8*)(At + (wr * 64 + mi * 16 + lr) * 32 + lh * 8);
#pragma unroll
    for (int ni = 0; ni < 4; ni++)
      bfr[ni] = *(const bf16x8*)(Bt + (wc * 64 + ni * 16 + lr) * 32 + lh * 8);
#pragma unroll
    for (int mi = 0; mi < 4; mi++)
#pragma unroll
      for (int ni = 0; ni < 4; ni++)
        acc[mi][ni] = __builtin_amdgcn_mfma_f32_16x16x32_bf16(af[mi], bfr[ni], acc[mi][ni], 0, 0, 0);
    __syncthreads();
  }

#pragma unroll
  for (int mi = 0; mi < 4; mi++)
#pragma unroll
    for (int ni = 0; ni < 4; ni++)
#pragma unroll
      for (int i = 0; i < 4; i++) {
        int row = bm * 128 + wr * 64 + mi * 16 + lh * 4 + i;  // token
        int col = bn * 128 + wc * 64 + ni * 16 + lr;          // out feature
        float v = acc[mi][ni][i];
        if (MODE == 1) {
          outf[row * 1024 + col] = v;
        } else {
          int b = row >> 11, s = row & 2047, hh = col >> 6, hd = col & 63;
          int dst = ((b * NHEAD + hh) * NS + s) * NHD + hd;
          u16 hb = f2bf(v);
          if (z == 0)      { qh[dst] = hb; ql[dst] = f2bf(v - bf2f(hb)); }
          else if (z == 1) { kh[dst] = hb; kl[dst] = f2bf(v - bf2f(hb)); }
          else             { vh[dst] = hb; }   // V: single bf16, lo unused downstream
        }
      }
}

// ---------------- V transpose: vh[bh][s][d] -> vt[bh][d][s] ----------------
__global__ void k_vtrans(const u16* __restrict__ vh, u16* __restrict__ vt) {
  const int bh = blockIdx.y;
  const int s0 = blockIdx.x * 64;
  const int t = threadIdx.x;
  const int d = t >> 2, j0 = (t & 3) * 16;
  const u16* src = vh + bh * (NS * NHD) + (s0 + j0) * NHD + d;
  ushort8 a, b;
#pragma unroll
  for (int j = 0; j < 8; j++) a[j] = src[j * NHD];
#pragma unroll
  for (int j = 0; j < 8; j++) b[j] = src[(8 + j) * NHD];
  u16* dst = vt + bh * (NHD * NS) + d * NS + s0 + j0;
  *(ushort8*)dst = a;
  *(ushort8*)(dst + 8) = b;
}

// ---------------- RoPE (in-place on hi/lo pairs), precise trig --------------
__global__ void k_rope(const int* __restrict__ pos_ids,
                       u16* __restrict__ qh, u16* __restrict__ ql,
                       u16* __restrict__ kh, u16* __restrict__ kl) {
  int gid = blockIdx.x * 256 + threadIdx.x;
  int row = gid >> 5, d = gid & 31;          // row in [0, B*NH*S)
  int bh = row >> 11, s = row & 2047, b = bh >> 4;
  int pos = pos_ids[b * NS + s];
  float inv = 1.0f / powf(10000.0f, (float)(2 * d) / 64.0f);
  float fr = (float)pos * inv;
  float c = cosf(fr), sn = sinf(fr);
  int off = row * 64 + d;
  {
    float x1 = bf2f(qh[off]) + bf2f(ql[off]);
    float x2 = bf2f(qh[off + 32]) + bf2f(ql[off + 32]);
    float n1 = x1 * c - x2 * sn;
    float n2 = x2 * c + x1 * sn;
    u16 h1 = f2bf(n1); qh[off] = h1;       ql[off] = f2bf(n1 - bf2f(h1));
    u16 h2 = f2bf(n2); qh[off + 32] = h2;  ql[off + 32] = f2bf(n2 - bf2f(h2));
  }
  {
    float x1 = bf2f(kh[off]) + bf2f(kl[off]);
    float x2 = bf2f(kh[off + 32]) + bf2f(kl[off + 32]);
    float n1 = x1 * c - x2 * sn;
    float n2 = x2 * c + x1 * sn;
    u16 h1 = f2bf(n1); kh[off] = h1;       kl[off] = f2bf(n1 - bf2f(h1));
    u16 h2 = f2bf(n2); kh[off + 32] = h2;  kl[off + 32] = f2bf(n2 - bf2f(h2));
  }
}

// ---------------- flash attention, 1 wave per 32 q-rows, KBLK=64 ------------
// K/V fragments loaded DIRECTLY from global (L2-resident: 768KB per bh).
// V pre-transposed in global (vt[bh][d][s]) so B-frags are contiguous 16B.
// No barriers anywhere; only per-wave-private P goes through LDS.
// Q pre-scaled by 0.125*log2(e) (f32 re-split keeps hi/lo exact) -> raw exp2.
__global__ __launch_bounds__(64) void k_attn(
    const u16* __restrict__ qh, const u16* __restrict__ ql,
    const u16* __restrict__ kh, const u16* __restrict__ kl,
    const u16* __restrict__ vt, float* __restrict__ ao) {
  __shared__ __attribute__((aligned(16))) u16 Pl[32 * 64];
  const int lane = threadIdx.x;
  const int lr = lane & 15, lh = lane >> 4;
  const int qt = blockIdx.x, bh = blockIdx.y;
  const int b = bh >> 4, hco = (bh & 15) * NHD;
  const int base = bh * (NS * NHD);
  const int qbase = qt * 32;

  const float SC = 0.125f * 1.4426950408889634f;  // -> log2 domain
  bf16x8 qfh[2][2], qfl[2][2];
#pragma unroll
  for (int rf = 0; rf < 2; rf++)
#pragma unroll
    for (int ks = 0; ks < 2; ks++) {
      int off = base + (qbase + rf * 16 + lr) * NHD + ks * 32 + lh * 8;
      ushort8 hu = *(const ushort8*)(qh + off);
      ushort8 lu = *(const ushort8*)(ql + off);
      union { ushort8 u; bf16x8 b; } H, L;
#pragma unroll
      for (int j = 0; j < 8; j++) {
        float f = (bf2f(hu[j]) + bf2f(lu[j])) * SC;
        u16 hb = f2bf(f);
        H.u[j] = hb;
        L.u[j] = f2bf(f - bf2f(hb));
      }
      qfh[rf][ks] = H.b;
      qfl[rf][ks] = L.b;
    }

  floatx4 acco[2][4];
  float m_r[2][4], l_r[2][4];
#pragma unroll
  for (int rf = 0; rf < 2; rf++) {
#pragma unroll
    for (int df = 0; df < 4; df++) acco[rf][df] = (floatx4){0.f, 0.f, 0.f, 0.f};
#pragma unroll
    for (int i = 0; i < 4; i++) { m_r[rf][i] = -1e30f; l_r[rf][i] = 0.f; }
  }
  char* Pw = (char*)Pl;

  const u16* kh_l = kh + base + lr * NHD + lh * 8;
  const u16* kl_l = kl + base + lr * NHD + lh * 8;
  const u16* vt_l = vt + base + lr * NS + lh * 8;  // row d=lr (+df*16 later)

  for (int kt = 0; kt < 32; ++kt) {
    const int key0 = kt * 64;

    // ---- S = Q K^T (3-term hi/lo), K frags straight from global ----
    floatx4 sac[2][4];
#pragma unroll
    for (int rf = 0; rf < 2; rf++)
#pragma unroll
      for (int cf = 0; cf < 4; cf++) sac[rf][cf] = (floatx4){0.f, 0.f, 0.f, 0.f};
#pragma unroll
    for (int cf = 0; cf < 4; cf++) {
      const int krow = (key0 + cf * 16) * NHD;
      bf16x8 bh0 = *(const bf16x8*)(kh_l + krow);
      bf16x8 bh1 = *(const bf16x8*)(kh_l + krow + 32);
      bf16x8 bl0 = *(const bf16x8*)(kl_l + krow);
      bf16x8 bl1 = *(const bf16x8*)(kl_l + krow + 32);
      __builtin_amdgcn_s_setprio(1);
#pragma unroll
      for (int rf = 0; rf < 2; rf++) {
        sac[rf][cf] = __builtin_amdgcn_mfma_f32_16x16x32_bf16(qfh[rf][0], bh0, sac[rf][cf], 0, 0, 0);
        sac[rf][cf] = __builtin_amdgcn_mfma_f32_16x16x32_bf16(qfh[rf][1], bh1, sac[rf][cf], 0, 0, 0);
        sac[rf][cf] = __builtin_amdgcn_mfma_f32_16x16x32_bf16(qfh[rf][0], bl0, sac[rf][cf], 0, 0, 0);
        sac[rf][cf] = __builtin_amdgcn_mfma_f32_16x16x32_bf16(qfh[rf][1], bl1, sac[rf][cf], 0, 0, 0);
        sac[rf][cf] = __builtin_amdgcn_mfma_f32_16x16x32_bf16(qfl[rf][0], bh0, sac[rf][cf], 0, 0, 0);
        sac[rf][cf] = __builtin_amdgcn_mfma_f32_16x16x32_bf16(qfl[rf][1], bh1, sac[rf][cf], 0, 0, 0);
      }
      __builtin_amdgcn_s_setprio(0);
    }

    // ---- online softmax (raw log2 domain; rows in 16-lane groups) ----
#pragma unroll
    for (int rf = 0; rf < 2; rf++) {
      float al[4];
#pragma unroll
      for (int i = 0; i < 4; i++) {
        float mt = fmaxf(fmaxf(sac[rf][0][i], sac[rf][1][i]),
                         fmaxf(sac[rf][2][i], sac[rf][3][i]));
#pragma unroll
        for (int off = 1; off < 16; off <<= 1) mt = fmaxf(mt, __shfl_xor(mt, off));
        float mn = fmaxf(m_r[rf][i], mt);
        al[i] = exp2f(m_r[rf][i] - mn);
        float rs = 0.f;
#pragma unroll
        for (int cf = 0; cf < 4; cf++) {
          float pv = exp2f(sac[rf][cf][i] - mn);
          sac[rf][cf][i] = pv;
          rs += pv;
        }
#pragma unroll
        for (int off = 1; off < 16; off <<= 1) rs += __shfl_xor(rs, off);
        l_r[rf][i] = l_r[rf][i] * al[i] + rs;
        m_r[rf][i] = mn;
      }
#pragma unroll
      for (int df = 0; df < 4; df++) {
        floatx4 t = acco[rf][df];
#pragma unroll
        for (int i = 0; i < 4; i++) t[i] *= al[i];
        acco[rf][df] = t;
      }
#pragma unroll
      for (int cf = 0; cf < 4; cf++)
#pragma unroll
        for (int i = 0; i < 4; i++) {
          int prow = rf * 16 + lh * 4 + i;
          int pcol = cf * 16 + lr;
          *(u16*)(Pw + prow * 128 + ((pcol * 2) ^ ((prow & 7) << 4))) = f2bf(sac[rf][cf][i]);
        }
    }

    // ---- O += P V  (V^T frags straight from global) ----
#pragma unroll
    for (int ks = 0; ks < 2; ks++) {
      bf16x8 vf[4];
#pragma unroll
      for (int df = 0; df < 4; df++)
        vf[df] = *(const bf16x8*)(vt_l + df * 16 * NS + key0 + ks * 32);
      bf16x8 pf[2];
#pragma unroll
      for (int rf = 0; rf < 2; rf++) {
        int prow = rf * 16 + lr;
        pf[rf] = *(const bf16x8*)((const char*)Pw + prow * 128 + (((ks * 32 + lh * 8) * 2) ^ ((prow & 7) << 4)));
      }
      __builtin_amdgcn_s_setprio(1);
#pragma unroll
      for (int rf = 0; rf < 2; rf++)
#pragma unroll
        for (int df = 0; df < 4; df++)
          acco[rf][df] = __builtin_amdgcn_mfma_f32_16x16x32_bf16(pf[rf], vf[df], acco[rf][df], 0, 0, 0);
      __builtin_amdgcn_s_setprio(0);
    }
  }

#pragma unroll
  for (int rf = 0; rf < 2; rf++)
#pragma unroll
    for (int df = 0; df < 4; df++)
#pragma unroll
      for (int i = 0; i < 4; i++) {
        int row = qbase + rf * 16 + lh * 4 + i;
        int col = hco + df * 16 + lr;
        ao[(b * NS + row) * NHID + col] = acco[rf][df][i] / l_r[rf][i];
      }
}

__global__ void k_scale(const double* __restrict__ sums, const float* __restrict__ hss,
                        float* __restrict__ out) {
  if (threadIdx.x == 0) {
    float sv = (float)(sums[2] / (double)WELEM) + 1e-5f;
    float so = (float)(sums[3] / (double)WELEM) + 1e-5f;
    out[NTOK * NHID] = hss[0] * sv * so;
  }
}

extern "C" void kernel_launch(void* const* d_in, const int* in_sizes, int n_in,
                              void* d_out, int out_size, void* d_ws, size_t ws_size,
                              hipStream_t stream) {
  const float* x   = (const float*)d_in[0];
  const float* hss = (const float*)d_in[1];
  const int*   pos = (const int*)d_in[2];
  const float* wq  = (const float*)d_in[3];
  const float* wk  = (const float*)d_in[4];
  const float* wv  = (const float*)d_in[5];
  const float* wo  = (const float*)d_in[6];
  float* out = (float*)d_out;
  char* ws = (char*)d_ws;
  const size_t MB = 1u << 20;
  u16* wt = (u16*)(ws);              // 4 ternary matrices, 8MB
  u16* xh = (u16*)(ws + 8 * MB);
  u16* xl = (u16*)(ws + 16 * MB);
  u16* qh = (u16*)(ws + 24 * MB);
  u16* ql = (u16*)(ws + 32 * MB);
  u16* kh = (u16*)(ws + 40 * MB);
  u16* kl = (u16*)(ws + 48 * MB);
  u16* vh = (u16*)(ws + 56 * MB);
  u16* vt = (u16*)(ws + 64 * MB);    // transposed V [bh][d][s]
  float* ao = (float*)(ws + 72 * MB);  // 16MB
  double* sums = (double*)(ws + 88 * MB);
  u16* aoh = xh;  // x no longer needed after QKV proj
  u16* aol = xl;

  k_init<<<1, 64, 0, stream>>>(sums);
  k_abssum<<<dim3(256, 4), 256, 0, stream>>>(wq, wk, wv, wo, sums);
  k_quant<<<dim3(1024, 4), 256, 0, stream>>>(wq, wk, wv, wo, sums, wt);
  k_split<<<4096, 256, 0, stream>>>(x, xh, xl);
  k_gemm<0><<<dim3(32, 8, 3), 256, 0, stream>>>(xh, xl, wt, nullptr, qh, ql, kh, kl, vh, nullptr);
  k_vtrans<<<dim3(32, 32), 256, 0, stream>>>(vh, vt);
  k_rope<<<8192, 256, 0, stream>>>(pos, qh, ql, kh, kl);
  k_attn<<<dim3(64, 32), 64, 0, stream>>>(qh, ql, kh, kl, vt, ao);
  k_split<<<4096, 256, 0, stream>>>(ao, aoh, aol);
  k_gemm<1><<<dim3(32, 8, 1), 256, 0, stream>>>(aoh, aol, wt, out,
                                                nullptr, nullptr, nullptr, nullptr, nullptr, nullptr);
  k_scale<<<1, 64, 0, stream>>>(sums, hss, out);
}

// Round 4
// 276.817 us; speedup vs baseline: 1.2521x; 1.2521x over previous
//
#include <hip/hip_runtime.h>
#include <hip/hip_bf16.h>

// BitNetAttention: B=2,S=2048,HID=1024,NH=16,HD=64
#define NB 2
#define NS 2048
#define NHID 1024
#define NHEAD 16
#define NHD 64
#define NTOK (NB*NS)        // 4096
#define WELEM (NHID*NHID)   // 1048576

typedef unsigned short u16;
typedef __attribute__((ext_vector_type(4))) float floatx4;
typedef __attribute__((ext_vector_type(16))) float floatx16;
typedef __attribute__((ext_vector_type(8))) __bf16 bf16x8;
typedef __attribute__((ext_vector_type(8))) unsigned short ushort8;

__device__ __forceinline__ u16 f2bf(float f) {
  union { float f; unsigned u; } a; a.f = f;
  unsigned u = a.u;
  unsigned r = (u + 0x7fffu + ((u >> 16) & 1u)) >> 16;  // RNE
  return (u16)r;
}
__device__ __forceinline__ float bf2f(u16 s) {
  union { unsigned u; float f; } a; a.u = ((unsigned)s) << 16;
  return a.f;
}
__device__ __forceinline__ void gload16(const void* g, void* lds) {
  __builtin_amdgcn_global_load_lds(
      (const __attribute__((address_space(1))) unsigned int*)g,
      (__attribute__((address_space(3))) unsigned int*)lds, 16, 0, 0);
}
__device__ __forceinline__ unsigned pk2(float a, float b) {
  return (unsigned)f2bf(a) | ((unsigned)f2bf(b) << 16);
}

// ---------------- scale reduction (fp64 for boundary fidelity) --------------
__global__ void k_init(double* sums) { if (threadIdx.x < 4) sums[threadIdx.x] = 0.0; }

__global__ void k_abssum(const float* __restrict__ wq, const float* __restrict__ wk,
                         const float* __restrict__ wv, const float* __restrict__ wo,
                         double* __restrict__ sums) {
  const float* srcs[4] = {wq, wk, wv, wo};
  const float* w = srcs[blockIdx.y];
  int idx = (blockIdx.x * 256 + threadIdx.x) * 16;
  float s = 0.f;
#pragma unroll
  for (int j = 0; j < 4; j++) {
    float4 v = *(const float4*)(w + idx + j * 4);
    s += fabsf(v.x) + fabsf(v.y) + fabsf(v.z) + fabsf(v.w);
  }
#pragma unroll
  for (int off = 32; off; off >>= 1) s += __shfl_down(s, off);
  __shared__ float ps[4];
  if ((threadIdx.x & 63) == 0) ps[threadIdx.x >> 6] = s;
  __syncthreads();
  if (threadIdx.x == 0) atomicAdd(&sums[blockIdx.y], (double)(ps[0] + ps[1] + ps[2] + ps[3]));
}

__global__ void k_quant(const float* __restrict__ wq, const float* __restrict__ wk,
                        const float* __restrict__ wv, const float* __restrict__ wo,
                        const double* __restrict__ sums, u16* __restrict__ wt) {
  const float* srcs[4] = {wq, wk, wv, wo};
  const float* w = srcs[blockIdx.y];
  u16* dst = wt + blockIdx.y * WELEM;
  float s = (float)(sums[blockIdx.y] / (double)WELEM) + 1e-5f;
  int idx = (blockIdx.x * 256 + threadIdx.x) * 4;
  float4 v = *(const float4*)(w + idx);
  float f[4] = {v.x, v.y, v.z, v.w};
  union { u16 ss[4]; uint2 u; } O;
#pragma unroll
  for (int j = 0; j < 4; j++) {
    float q = rintf(f[j] / s);            // round-half-even, matches np.round
    q = fminf(1.f, fmaxf(-1.f, q));
    O.ss[j] = f2bf(q);                    // ternary exact in bf16
  }
  *(uint2*)(dst + idx) = O.u;
}

// ---------------- fp32 -> bf16 hi/lo split ---------------------------------
__global__ void k_split(const float* __restrict__ x, u16* __restrict__ hi, u16* __restrict__ lo) {
  int idx = (blockIdx.x * 256 + threadIdx.x) * 4;
  float4 v = *(const float4*)(x + idx);
  float f[4] = {v.x, v.y, v.z, v.w};
  union { u16 s[4]; uint2 u; } H, L;
#pragma unroll
  for (int j = 0; j < 4; j++) {
    u16 hb = f2bf(f[j]);
    H.s[j] = hb;
    L.s[j] = f2bf(f[j] - bf2f(hb));
  }
  *(uint2*)(hi + idx) = H.u;
  *(uint2*)(lo + idx) = L.u;
}

// ---------------- GEMM: C[m,o] = sum_k (Ahi+Alo)[m,k] * W[o,k] --------------
template <int MODE>
__global__ __launch_bounds__(256) void k_gemm(
    const u16* __restrict__ Ahi, const u16* __restrict__ Alo,
    const u16* __restrict__ Wt, float* __restrict__ outf,
    u16* __restrict__ qh, u16* __restrict__ ql,
    u16* __restrict__ kh, u16* __restrict__ kl,
    u16* __restrict__ vh, u16* __restrict__ vl) {
  __shared__ __attribute__((aligned(16))) u16 At[128 * 32];
  __shared__ __attribute__((aligned(16))) u16 Bt[128 * 32];
  const int tid = threadIdx.x;
  const int wave = tid >> 6, lane = tid & 63;
  const int lr = lane & 15, lh = lane >> 4;
  const int bm = blockIdx.x, bn = blockIdx.y, z = blockIdx.z;
  const u16* W = Wt + (MODE == 0 ? z : 3) * WELEM;
  const int wr = wave >> 1, wc = wave & 1;

  floatx4 acc[4][4];
#pragma unroll
  for (int i = 0; i < 4; i++)
#pragma unroll
    for (int j = 0; j < 4; j++) acc[i][j] = (floatx4){0.f, 0.f, 0.f, 0.f};

  const int e0 = tid * 8;
  const int row0 = e0 >> 5, col0 = e0 & 31;

  for (int kt = 0; kt < 64; ++kt) {  // K_eff = 2048 = [hi | lo]
    const u16* Asrc = (kt < 32) ? Ahi : Alo;
    const int k0 = (kt & 31) * 32;
#pragma unroll
    for (int it = 0; it < 2; ++it) {
      int row = row0 + it * 64;
      gload16(Asrc + (bm * 128 + row) * 1024 + k0 + col0, (char*)At + it * 4096 + wave * 1024);
      gload16(W    + (bn * 128 + row) * 1024 + k0 + col0, (char*)Bt + it * 4096 + wave * 1024);
    }
    __syncthreads();
    bf16x8 af[4], bfr[4];
#pragma unroll
    for (int mi = 0; mi < 4; mi++)
      af[mi] = *(const bf16x8*)(At + (wr * 64 + mi * 16 + lr) * 32 + lh * 8);
#pragma unroll
    for (int ni = 0; ni < 4; ni++)
      bfr[ni] = *(const bf16x8*)(Bt + (wc * 64 + ni * 16 + lr) * 32 + lh * 8);
#pragma unroll
    for (int mi = 0; mi < 4; mi++)
#pragma unroll
      for (int ni = 0; ni < 4; ni++)
        acc[mi][ni] = __builtin_amdgcn_mfma_f32_16x16x32_bf16(af[mi], bfr[ni], acc[mi][ni], 0, 0, 0);
    __syncthreads();
  }

#pragma unroll
  for (int mi = 0; mi < 4; mi++)
#pragma unroll
    for (int ni = 0; ni < 4; ni++)
#pragma unroll
      for (int i = 0; i < 4; i++) {
        int row = bm * 128 + wr * 64 + mi * 16 + lh * 4 + i;  // token
        int col = bn * 128 + wc * 64 + ni * 16 + lr;          // out feature
        float v = acc[mi][ni][i];
        if (MODE == 1) {
          outf[row * 1024 + col] = v;
        } else {
          int b = row >> 11, s = row & 2047, hh = col >> 6, hd = col & 63;
          int dst = ((b * NHEAD + hh) * NS + s) * NHD + hd;
          u16 hb = f2bf(v);
          if (z == 0)      { qh[dst] = hb; ql[dst] = f2bf(v - bf2f(hb)); }
          else if (z == 1) { kh[dst] = hb; kl[dst] = f2bf(v - bf2f(hb)); }
          else             { vh[dst] = hb; }   // V: single bf16
        }
      }
}

// ---------------- V transpose: vh[bh][s][d] -> vt[bh][d][s] ----------------
__global__ void k_vtrans(const u16* __restrict__ vh, u16* __restrict__ vt) {
  const int bh = blockIdx.y;
  const int s0 = blockIdx.x * 64;
  const int t = threadIdx.x;
  const int d = t >> 2, j0 = (t & 3) * 16;
  const u16* src = vh + bh * (NS * NHD) + (s0 + j0) * NHD + d;
  ushort8 a, b;
#pragma unroll
  for (int j = 0; j < 8; j++) a[j] = src[j * NHD];
#pragma unroll
  for (int j = 0; j < 8; j++) b[j] = src[(8 + j) * NHD];
  u16* dst = vt + bh * (NHD * NS) + d * NS + s0 + j0;
  *(ushort8*)dst = a;
  *(ushort8*)(dst + 8) = b;
}

// ---------------- RoPE (in-place on hi/lo pairs), precise trig --------------
__global__ void k_rope(const int* __restrict__ pos_ids,
                       u16* __restrict__ qh, u16* __restrict__ ql,
                       u16* __restrict__ kh, u16* __restrict__ kl) {
  int gid = blockIdx.x * 256 + threadIdx.x;
  int row = gid >> 5, d = gid & 31;          // row in [0, B*NH*S)
  int bh = row >> 11, s = row & 2047, b = bh >> 4;
  int pos = pos_ids[b * NS + s];
  float inv = 1.0f / powf(10000.0f, (float)(2 * d) / 64.0f);
  float fr = (float)pos * inv;
  float c = cosf(fr), sn = sinf(fr);
  int off = row * 64 + d;
  {
    float x1 = bf2f(qh[off]) + bf2f(ql[off]);
    float x2 = bf2f(qh[off + 32]) + bf2f(ql[off + 32]);
    float n1 = x1 * c - x2 * sn;
    float n2 = x2 * c + x1 * sn;
    u16 h1 = f2bf(n1); qh[off] = h1;       ql[off] = f2bf(n1 - bf2f(h1));
    u16 h2 = f2bf(n2); qh[off + 32] = h2;  ql[off + 32] = f2bf(n2 - bf2f(h2));
  }
  {
    float x1 = bf2f(kh[off]) + bf2f(kl[off]);
    float x2 = bf2f(kh[off + 32]) + bf2f(kl[off + 32]);
    float n1 = x1 * c - x2 * sn;
    float n2 = x2 * c + x1 * sn;
    u16 h1 = f2bf(n1); kh[off] = h1;       kl[off] = f2bf(n1 - bf2f(h1));
    u16 h2 = f2bf(n2); kh[off + 32] = h2;  kl[off + 32] = f2bf(n2 - bf2f(h2));
  }
}

// ---------------- flash attention: swapped-operand 32x32 MFMA ---------------
// 4 waves x 32 q-rows. KVBLK=64. QK^T computed as mfma(K, Q) -> lane owns
// one q-row (col=lane&31); softmax fully in-register; lane<->lane+32 merges
// via __shfl_xor(.,32) (ds_bpermute; no inline-asm hazards). P packed with
// scalar RNE packs + shfl exchange into PV B-frags; PV as mfma(V^T, P^T).
// K staged via global_load_lds + XOR swizzle; V^T frags direct from L2.
__global__ __launch_bounds__(256) void k_attn(
    const u16* __restrict__ qh, const u16* __restrict__ ql,
    const u16* __restrict__ kh, const u16* __restrict__ kl,
    const u16* __restrict__ vt, float* __restrict__ ao) {
  __shared__ __attribute__((aligned(16))) char SM[32768];
  const int tid = threadIdx.x, wave = tid >> 6, lane = tid & 63;
  const int l5 = lane & 31, hi = lane >> 5;
  const int qt = blockIdx.x, bh = blockIdx.y;
  const int b = bh >> 4, hco = (bh & 15) * NHD;
  const int base = bh * (NS * NHD);
  const int qrow = qt * 128 + wave * 32 + l5;
  const float SC = 0.125f * 1.4426950408889634f;  // log2 domain

  // Q B-frags: lane holds Q[qrow][s*16 + hi*8 + j], hi/lo re-split after scale
  bf16x8 qfh[4], qfl[4];
#pragma unroll
  for (int s = 0; s < 4; s++) {
    int off = base + qrow * NHD + s * 16 + hi * 8;
    ushort8 hu = *(const ushort8*)(qh + off);
    ushort8 lu = *(const ushort8*)(ql + off);
    union { ushort8 u; bf16x8 v; } H, L;
#pragma unroll
    for (int j = 0; j < 8; j++) {
      float f = (bf2f(hu[j]) + bf2f(lu[j])) * SC;
      u16 hb = f2bf(f);
      H.u[j] = hb; L.u[j] = f2bf(f - bf2f(hb));
    }
    qfh[s] = H.v; qfl[s] = L.v;
  }

  floatx16 acco[2];
#pragma unroll
  for (int dt = 0; dt < 2; dt++)
#pragma unroll
    for (int r = 0; r < 16; r++) acco[dt][r] = 0.f;
  float m_r = -1e30f, l_r = 0.f;

  const char* khg0 = (const char*)(kh + base);
  const char* klg0 = (const char*)(kl + base);

  for (int kt = 0; kt < 32; ++kt) {
    const int key0 = kt * 64;
    const char* khg = khg0 + key0 * 128;   // 128 B per key row
    const char* klg = klg0 + key0 * 128;
#pragma unroll
    for (int it = 0; it < 2; ++it) {
      int L = it * 4096 + tid * 16;
      int g = L ^ (((L >> 7) & 7) << 4);   // pre-swizzled source, linear dest
      gload16(khg + g, SM + it * 4096 + wave * 1024);
      gload16(klg + g, SM + 8192 + it * 4096 + wave * 1024);
    }
    __syncthreads();

    // prefetch V^T A-frags from global (L2): consumed after softmax
    bf16x8 vtf[2][4];
#pragma unroll
    for (int dt = 0; dt < 2; dt++)
#pragma unroll
      for (int s = 0; s < 4; s++)
        vtf[dt][s] = *(const bf16x8*)(vt + base + (l5 + 32 * dt) * NS + key0 + s * 16 + hi * 8);

    // S^T = K Q^T : 3-term hi/lo, 24 mfma32
    floatx16 sacc[2];
#pragma unroll
    for (int t = 0; t < 2; t++)
#pragma unroll
      for (int r = 0; r < 16; r++) sacc[t][r] = 0.f;
#pragma unroll
    for (int t = 0; t < 2; t++) {
      const int row = 32 * t + l5;
      const int swz = (row & 7) << 4;
#pragma unroll
      for (int s = 0; s < 4; s++) {
        int byt = row * 128 + ((s * 32 + hi * 16) ^ swz);
        bf16x8 ah = *(const bf16x8*)(SM + byt);
        bf16x8 al8 = *(const bf16x8*)(SM + 8192 + byt);
        __builtin_amdgcn_s_setprio(1);
        sacc[t] = __builtin_amdgcn_mfma_f32_32x32x16_bf16(ah, qfh[s], sacc[t], 0, 0, 0);
        sacc[t] = __builtin_amdgcn_mfma_f32_32x32x16_bf16(ah, qfl[s], sacc[t], 0, 0, 0);
        sacc[t] = __builtin_amdgcn_mfma_f32_32x32x16_bf16(al8, qfh[s], sacc[t], 0, 0, 0);
        __builtin_amdgcn_s_setprio(0);
      }
    }

    // ---- in-register online softmax (lane owns q-row = l5) ----------------
    float mt = sacc[0][0];
#pragma unroll
    for (int r = 1; r < 16; r++) mt = fmaxf(mt, sacc[0][r]);
#pragma unroll
    for (int r = 0; r < 16; r++) mt = fmaxf(mt, sacc[1][r]);
    mt = fmaxf(mt, __shfl_xor(mt, 32));       // merge lane<->lane+32 halves
    if (!__all(mt <= m_r + 8.0f)) {           // defer-max (T13)
      float mn = fmaxf(m_r, mt);
      float sc2 = exp2f(m_r - mn);
      l_r *= sc2;
#pragma unroll
      for (int dt = 0; dt < 2; dt++)
#pragma unroll
        for (int r = 0; r < 16; r++) acco[dt][r] *= sc2;
      m_r = mn;
    }
    float ls = 0.f;
#pragma unroll
    for (int t = 0; t < 2; t++)
#pragma unroll
      for (int r = 0; r < 16; r++) {
        float p = exp2f(sacc[t][r] - m_r);
        sacc[t][r] = p; ls += p;
      }
    ls += __shfl_xor(ls, 32);
    l_r += ls;

    // ---- pack P (scalar RNE pack + shfl_xor(32) exchange), then PV --------
#pragma unroll
    for (int s = 0; s < 4; s++) {
      int t = s >> 1, rb = (s & 1) * 8;
      unsigned w01 = pk2(sacc[t][rb + 0], sacc[t][rb + 1]);
      unsigned w23 = pk2(sacc[t][rb + 2], sacc[t][rb + 3]);
      unsigned w45 = pk2(sacc[t][rb + 4], sacc[t][rb + 5]);
      unsigned w67 = pk2(sacc[t][rb + 6], sacc[t][rb + 7]);
      unsigned t01 = __shfl_xor(w45, 32);   // partner's w45 -> my w01 (hi lanes)
      unsigned t45 = __shfl_xor(w01, 32);   // partner's w01 -> my w45 (lo lanes)
      unsigned t23 = __shfl_xor(w67, 32);
      unsigned t67 = __shfl_xor(w23, 32);
      union { unsigned u[4]; bf16x8 v; } P;
      P.u[0] = hi ? t01 : w01;
      P.u[1] = hi ? t23 : w23;
      P.u[2] = hi ? w45 : t45;
      P.u[3] = hi ? w67 : t67;
      __builtin_amdgcn_s_setprio(1);
      acco[0] = __builtin_amdgcn_mfma_f32_32x32x16_bf16(vtf[0][s], P.v, acco[0], 0, 0, 0);
      acco[1] = __builtin_amdgcn_mfma_f32_32x32x16_bf16(vtf[1][s], P.v, acco[1], 0, 0, 0);
      __builtin_amdgcn_s_setprio(0);
    }
    __syncthreads();
  }

  // ---- O write: XOR-swizzled LDS transpose -> coalesced stores -------------
  float inv = 1.0f / l_r;
  float* OT = (float*)SM;
#pragma unroll
  for (int dt = 0; dt < 2; dt++)
#pragma unroll
    for (int r = 0; r < 16; r++) {
      int col = (r & 3) + 8 * (r >> 2) + 4 * hi + 32 * dt;  // d
      int cs = (col & 32) | ((col ^ l5) & 31);
      OT[(wave * 32 + l5) * 64 + cs] = acco[dt][r] * inv;
    }
  __syncthreads();
  {
    int row = tid >> 1, h = tid & 1;
    float vb[32];
#pragma unroll
    for (int j = 0; j < 32; j++) {
      int c = h * 32 + j;
      int cs = (c & 32) | ((c ^ (row & 31)) & 31);
      vb[j] = OT[row * 64 + cs];
    }
    float* dst = ao + ((size_t)(b * NS + qt * 128 + row)) * NHID + hco + h * 32;
#pragma unroll
    for (int j2 = 0; j2 < 8; j2++) {
      float4 o4 = {vb[4 * j2], vb[4 * j2 + 1], vb[4 * j2 + 2], vb[4 * j2 + 3]};
      *(float4*)(dst + 4 * j2) = o4;
    }
  }
}

__global__ void k_scale(const double* __restrict__ sums, const float* __restrict__ hss,
                        float* __restrict__ out) {
  if (threadIdx.x == 0) {
    float sv = (float)(sums[2] / (double)WELEM) + 1e-5f;
    float so = (float)(sums[3] / (double)WELEM) + 1e-5f;
    out[NTOK * NHID] = hss[0] * sv * so;
  }
}

extern "C" void kernel_launch(void* const* d_in, const int* in_sizes, int n_in,
                              void* d_out, int out_size, void* d_ws, size_t ws_size,
                              hipStream_t stream) {
  const float* x   = (const float*)d_in[0];
  const float* hss = (const float*)d_in[1];
  const int*   pos = (const int*)d_in[2];
  const float* wq  = (const float*)d_in[3];
  const float* wk  = (const float*)d_in[4];
  const float* wv  = (const float*)d_in[5];
  const float* wo  = (const float*)d_in[6];
  float* out = (float*)d_out;
  char* ws = (char*)d_ws;
  const size_t MB = 1u << 20;
  u16* wt = (u16*)(ws);              // 4 ternary matrices, 8MB
  u16* xh = (u16*)(ws + 8 * MB);
  u16* xl = (u16*)(ws + 16 * MB);
  u16* qh = (u16*)(ws + 24 * MB);
  u16* ql = (u16*)(ws + 32 * MB);
  u16* kh = (u16*)(ws + 40 * MB);
  u16* kl = (u16*)(ws + 48 * MB);
  u16* vh = (u16*)(ws + 56 * MB);
  u16* vt = (u16*)(ws + 64 * MB);    // transposed V [bh][d][s]
  float* ao = (float*)(ws + 72 * MB);  // 16MB
  double* sums = (double*)(ws + 88 * MB);
  u16* aoh = xh;  // x no longer needed after QKV proj
  u16* aol = xl;

  k_init<<<1, 64, 0, stream>>>(sums);
  k_abssum<<<dim3(256, 4), 256, 0, stream>>>(wq, wk, wv, wo, sums);
  k_quant<<<dim3(1024, 4), 256, 0, stream>>>(wq, wk, wv, wo, sums, wt);
  k_split<<<4096, 256, 0, stream>>>(x, xh, xl);
  k_gemm<0><<<dim3(32, 8, 3), 256, 0, stream>>>(xh, xl, wt, nullptr, qh, ql, kh, kl, vh, nullptr);
  k_vtrans<<<dim3(32, 32), 256, 0, stream>>>(vh, vt);
  k_rope<<<8192, 256, 0, stream>>>(pos, qh, ql, kh, kl);
  k_attn<<<dim3(16, 32), 256, 0, stream>>>(qh, ql, kh, kl, vt, ao);
  k_split<<<4096, 256, 0, stream>>>(ao, aoh, aol);
  k_gemm<1><<<dim3(32, 8, 1), 256, 0, stream>>>(aoh, aol, wt, out,
                                                nullptr, nullptr, nullptr, nullptr, nullptr, nullptr);
  k_scale<<<1, 64, 0, stream>>>(sums, hss, out);
}

// Round 5
// 247.246 us; speedup vs baseline: 1.4018x; 1.1196x over previous
//
#include <hip/hip_runtime.h>
#include <hip/hip_bf16.h>

// BitNetAttention: B=2,S=2048,HID=1024,NH=16,HD=64
#define NB 2
#define NS 2048
#define NHID 1024
#define NHEAD 16
#define NHD 64
#define NTOK (NB*NS)        // 4096
#define WELEM (NHID*NHID)   // 1048576

typedef unsigned short u16;
typedef __attribute__((ext_vector_type(4))) float floatx4;
typedef __attribute__((ext_vector_type(16))) float floatx16;
typedef __attribute__((ext_vector_type(8))) __bf16 bf16x8;
typedef __attribute__((ext_vector_type(8))) unsigned short ushort8;
typedef __attribute__((ext_vector_type(2))) unsigned uint2v;

__device__ __forceinline__ u16 f2bf(float f) {
  union { float f; unsigned u; } a; a.f = f;
  unsigned u = a.u;
  unsigned r = (u + 0x7fffu + ((u >> 16) & 1u)) >> 16;  // RNE
  return (u16)r;
}
__device__ __forceinline__ float bf2f(u16 s) {
  union { unsigned u; float f; } a; a.u = ((unsigned)s) << 16;
  return a.f;
}
__device__ __forceinline__ void gload16(const void* g, void* lds) {
  __builtin_amdgcn_global_load_lds(
      (const __attribute__((address_space(1))) unsigned int*)g,
      (__attribute__((address_space(3))) unsigned int*)lds, 16, 0, 0);
}
// v_permlane32_swap_b32 builtin: vdst[32:63] <-> src[0:31]; returns {vdst', src'}
__device__ __forceinline__ uint2v pl32(unsigned a, unsigned b) {
  return __builtin_amdgcn_permlane32_swap(a, b, false, false);
}
__device__ __forceinline__ float mergemax(float x) {
  uint2v r = pl32(__float_as_uint(x), __float_as_uint(x));
  return fmaxf(__uint_as_float(r[0]), __uint_as_float(r[1]));
}
__device__ __forceinline__ float mergesum(float x) {
  uint2v r = pl32(__float_as_uint(x), __float_as_uint(x));
  return __uint_as_float(r[0]) + __uint_as_float(r[1]);
}

// ---------------- scale reduction (fp64 for boundary fidelity) --------------
__global__ void k_init(double* sums) { if (threadIdx.x < 4) sums[threadIdx.x] = 0.0; }

__global__ void k_abssum(const float* __restrict__ wq, const float* __restrict__ wk,
                         const float* __restrict__ wv, const float* __restrict__ wo,
                         double* __restrict__ sums) {
  const float* srcs[4] = {wq, wk, wv, wo};
  const float* w = srcs[blockIdx.y];
  int idx = (blockIdx.x * 256 + threadIdx.x) * 16;
  float s = 0.f;
#pragma unroll
  for (int j = 0; j < 4; j++) {
    float4 v = *(const float4*)(w + idx + j * 4);
    s += fabsf(v.x) + fabsf(v.y) + fabsf(v.z) + fabsf(v.w);
  }
#pragma unroll
  for (int off = 32; off; off >>= 1) s += __shfl_down(s, off);
  __shared__ float ps[4];
  if ((threadIdx.x & 63) == 0) ps[threadIdx.x >> 6] = s;
  __syncthreads();
  if (threadIdx.x == 0) atomicAdd(&sums[blockIdx.y], (double)(ps[0] + ps[1] + ps[2] + ps[3]));
}

__global__ void k_quant(const float* __restrict__ wq, const float* __restrict__ wk,
                        const float* __restrict__ wv, const float* __restrict__ wo,
                        const double* __restrict__ sums, u16* __restrict__ wt) {
  const float* srcs[4] = {wq, wk, wv, wo};
  const float* w = srcs[blockIdx.y];
  u16* dst = wt + blockIdx.y * WELEM;
  float s = (float)(sums[blockIdx.y] / (double)WELEM) + 1e-5f;
  int idx = (blockIdx.x * 256 + threadIdx.x) * 4;
  float4 v = *(const float4*)(w + idx);
  float f[4] = {v.x, v.y, v.z, v.w};
  union { u16 ss[4]; uint2 u; } O;
#pragma unroll
  for (int j = 0; j < 4; j++) {
    float q = rintf(f[j] / s);            // round-half-even, matches np.round
    q = fminf(1.f, fmaxf(-1.f, q));
    O.ss[j] = f2bf(q);                    // ternary exact in bf16
  }
  *(uint2*)(dst + idx) = O.u;
}

// ---------------- fp32 -> bf16 hi/lo split ---------------------------------
__global__ void k_split(const float* __restrict__ x, u16* __restrict__ hi, u16* __restrict__ lo) {
  int idx = (blockIdx.x * 256 + threadIdx.x) * 4;
  float4 v = *(const float4*)(x + idx);
  float f[4] = {v.x, v.y, v.z, v.w};
  union { u16 s[4]; uint2 u; } H, L;
#pragma unroll
  for (int j = 0; j < 4; j++) {
    u16 hb = f2bf(f[j]);
    H.s[j] = hb;
    L.s[j] = f2bf(f[j] - bf2f(hb));
  }
  *(uint2*)(hi + idx) = H.u;
  *(uint2*)(lo + idx) = L.u;
}

// ---------------- GEMM: C[m,o] = sum_k (Ahi+Alo)[m,k] * W[o,k] --------------
// Double-buffered, one barrier/iter, W staged ONCE per k-tile (shared by
// the hi and lo MFMA terms). LDS: 2 bufs x {Ah,Al,B} x 8KB = 48KB.
template <int MODE>
__global__ __launch_bounds__(256) void k_gemm(
    const u16* __restrict__ Ahi, const u16* __restrict__ Alo,
    const u16* __restrict__ Wt, float* __restrict__ outf,
    u16* __restrict__ qh, u16* __restrict__ ql,
    u16* __restrict__ kh, u16* __restrict__ kl,
    u16* __restrict__ vh) {
  __shared__ __attribute__((aligned(16))) char GSM[49152];
  const int tid = threadIdx.x;
  const int wave = tid >> 6, lane = tid & 63;
  const int lr = lane & 15, lh = lane >> 4;
  const int bm = blockIdx.x, bn = blockIdx.y, z = blockIdx.z;
  const u16* W = Wt + (MODE == 0 ? z : 3) * WELEM;
  const int wr = wave >> 1, wc = wave & 1;

  floatx4 acc[4][4];
#pragma unroll
  for (int i = 0; i < 4; i++)
#pragma unroll
    for (int j = 0; j < 4; j++) acc[i][j] = (floatx4){0.f, 0.f, 0.f, 0.f};

  const int e0 = tid * 8;
  const int row0 = e0 >> 5, col0 = e0 & 31;

  // prologue: stage k-tile 0 into buf 0
#pragma unroll
  for (int it = 0; it < 2; ++it) {
    int row = row0 + it * 64;
    gload16(Ahi + (bm * 128 + row) * 1024 + col0, GSM + it * 4096 + wave * 1024);
    gload16(Alo + (bm * 128 + row) * 1024 + col0, GSM + 8192 + it * 4096 + wave * 1024);
    gload16(W   + (bn * 128 + row) * 1024 + col0, GSM + 16384 + it * 4096 + wave * 1024);
  }

  for (int kt = 0; kt < 32; ++kt) {  // K = 1024, 32-wide tiles
    __syncthreads();                 // stage(kt) complete; buf[kt-1] readers done
    const int cb = (kt & 1) * 24576;
    if (kt < 31) {
      const int nb2 = ((kt + 1) & 1) * 24576;
      const int k0 = (kt + 1) * 32;
#pragma unroll
      for (int it = 0; it < 2; ++it) {
        int row = row0 + it * 64;
        gload16(Ahi + (bm * 128 + row) * 1024 + k0 + col0, GSM + nb2 + it * 4096 + wave * 1024);
        gload16(Alo + (bm * 128 + row) * 1024 + k0 + col0, GSM + nb2 + 8192 + it * 4096 + wave * 1024);
        gload16(W   + (bn * 128 + row) * 1024 + k0 + col0, GSM + nb2 + 16384 + it * 4096 + wave * 1024);
      }
    }
    const u16* Ahp = (const u16*)(GSM + cb);
    const u16* Alp = (const u16*)(GSM + cb + 8192);
    const u16* Bp  = (const u16*)(GSM + cb + 16384);
    bf16x8 ah[4], al8[4], bfr[4];
#pragma unroll
    for (int mi = 0; mi < 4; mi++) {
      ah[mi]  = *(const bf16x8*)(Ahp + (wr * 64 + mi * 16 + lr) * 32 + lh * 8);
      al8[mi] = *(const bf16x8*)(Alp + (wr * 64 + mi * 16 + lr) * 32 + lh * 8);
    }
#pragma unroll
    for (int ni = 0; ni < 4; ni++)
      bfr[ni] = *(const bf16x8*)(Bp + (wc * 64 + ni * 16 + lr) * 32 + lh * 8);
#pragma unroll
    for (int mi = 0; mi < 4; mi++)
#pragma unroll
      for (int ni = 0; ni < 4; ni++) {
        acc[mi][ni] = __builtin_amdgcn_mfma_f32_16x16x32_bf16(ah[mi], bfr[ni], acc[mi][ni], 0, 0, 0);
        acc[mi][ni] = __builtin_amdgcn_mfma_f32_16x16x32_bf16(al8[mi], bfr[ni], acc[mi][ni], 0, 0, 0);
      }
  }

#pragma unroll
  for (int mi = 0; mi < 4; mi++)
#pragma unroll
    for (int ni = 0; ni < 4; ni++)
#pragma unroll
      for (int i = 0; i < 4; i++) {
        int row = bm * 128 + wr * 64 + mi * 16 + lh * 4 + i;  // token
        int col = bn * 128 + wc * 64 + ni * 16 + lr;          // out feature
        float v = acc[mi][ni][i];
        if (MODE == 1) {
          outf[row * 1024 + col] = v;
        } else {
          int b = row >> 11, s = row & 2047, hh = col >> 6, hd = col & 63;
          int dst = ((b * NHEAD + hh) * NS + s) * NHD + hd;
          u16 hb = f2bf(v);
          if (z == 0)      { qh[dst] = hb; ql[dst] = f2bf(v - bf2f(hb)); }
          else if (z == 1) { kh[dst] = hb; kl[dst] = f2bf(v - bf2f(hb)); }
          else             { vh[dst] = hb; }   // V: single bf16
        }
      }
}

// ---------------- V transpose: vh[bh][s][d] -> vt[bh][d][s] ----------------
__global__ void k_vtrans(const u16* __restrict__ vh, u16* __restrict__ vt) {
  const int bh = blockIdx.y;
  const int s0 = blockIdx.x * 64;
  const int t = threadIdx.x;
  const int d = t >> 2, j0 = (t & 3) * 16;
  const u16* src = vh + bh * (NS * NHD) + (s0 + j0) * NHD + d;
  ushort8 a, b;
#pragma unroll
  for (int j = 0; j < 8; j++) a[j] = src[j * NHD];
#pragma unroll
  for (int j = 0; j < 8; j++) b[j] = src[(8 + j) * NHD];
  u16* dst = vt + bh * (NHD * NS) + d * NS + s0 + j0;
  *(ushort8*)dst = a;
  *(ushort8*)(dst + 8) = b;
}

// ---------------- RoPE (in-place on hi/lo pairs) ----------------------------
__global__ void k_rope(const int* __restrict__ pos_ids,
                       u16* __restrict__ qh, u16* __restrict__ ql,
                       u16* __restrict__ kh, u16* __restrict__ kl) {
  int gid = blockIdx.x * 256 + threadIdx.x;
  int row = gid >> 5, d = gid & 31;          // row in [0, B*NH*S)
  int bh = row >> 11, s = row & 2047, b = bh >> 4;
  int pos = pos_ids[b * NS + s];
  // 1/10000^(2d/64) = 2^(-d*log2(10000)/32)
  float inv = exp2f((float)d * -0.4152410118609203f);
  float fr = (float)pos * inv;
  float sn, c;
  __sincosf(fr, &sn, &c);  // fast path; fallback accuracy checked by absmax
  c = cosf(fr); sn = sinf(fr);  // precise trig (overrides fast): keep exact ref match
  int off = row * 64 + d;
  {
    float x1 = bf2f(qh[off]) + bf2f(ql[off]);
    float x2 = bf2f(qh[off + 32]) + bf2f(ql[off + 32]);
    float n1 = x1 * c - x2 * sn;
    float n2 = x2 * c + x1 * sn;
    u16 h1 = f2bf(n1); qh[off] = h1;       ql[off] = f2bf(n1 - bf2f(h1));
    u16 h2 = f2bf(n2); qh[off + 32] = h2;  ql[off + 32] = f2bf(n2 - bf2f(h2));
  }
  {
    float x1 = bf2f(kh[off]) + bf2f(kl[off]);
    float x2 = bf2f(kh[off + 32]) + bf2f(kl[off + 32]);
    float n1 = x1 * c - x2 * sn;
    float n2 = x2 * c + x1 * sn;
    u16 h1 = f2bf(n1); kh[off] = h1;       kl[off] = f2bf(n1 - bf2f(h1));
    u16 h2 = f2bf(n2); kh[off + 32] = h2;  kl[off + 32] = f2bf(n2 - bf2f(h2));
  }
}

// ---------------- flash attention: swapped-operand 32x32 MFMA ---------------
// Double-buffered K (2x16KB), ONE barrier per kt. Lane owns q-row; softmax
// in-register; half-wave merges + P-word exchange via permlane32_swap builtin.
// P->bf16 via compiler casts (v_cvt_pk_bf16_f32). V^T frags direct from L2.
// Epilogue writes hi/lo bf16 (feeds W_o GEMM without a split pass).
__global__ __launch_bounds__(256) void k_attn(
    const u16* __restrict__ qh, const u16* __restrict__ ql,
    const u16* __restrict__ kh, const u16* __restrict__ kl,
    const u16* __restrict__ vt, u16* __restrict__ aoh, u16* __restrict__ aol) {
  __shared__ __attribute__((aligned(16))) char SM[32768];
  const int tid = threadIdx.x, wave = tid >> 6, lane = tid & 63;
  const int l5 = lane & 31, hi = lane >> 5;
  const int qt = blockIdx.x, bh = blockIdx.y;
  const int b = bh >> 4, hco = (bh & 15) * NHD;
  const int base = bh * (NS * NHD);
  const int qrow = qt * 128 + wave * 32 + l5;
  const float SC = 0.125f * 1.4426950408889634f;  // log2 domain

  // Q B-frags: lane holds Q[qrow][s*16 + hi*8 + j], hi/lo re-split after scale
  bf16x8 qfh[4], qfl[4];
#pragma unroll
  for (int s = 0; s < 4; s++) {
    int off = base + qrow * NHD + s * 16 + hi * 8;
    ushort8 hu = *(const ushort8*)(qh + off);
    ushort8 lu = *(const ushort8*)(ql + off);
    union { ushort8 u; bf16x8 v; } H, L;
#pragma unroll
    for (int j = 0; j < 8; j++) {
      float f = (bf2f(hu[j]) + bf2f(lu[j])) * SC;
      u16 hb = f2bf(f);
      H.u[j] = hb; L.u[j] = f2bf(f - bf2f(hb));
    }
    qfh[s] = H.v; qfl[s] = L.v;
  }

  floatx16 acco[2];
#pragma unroll
  for (int dt = 0; dt < 2; dt++)
#pragma unroll
    for (int r = 0; r < 16; r++) acco[dt][r] = 0.f;
  float m_r = -1e30f, l_r = 0.f;

  const char* khg0 = (const char*)(kh + base);
  const char* klg0 = (const char*)(kl + base);

  // prologue: stage kt=0 into buf 0
#pragma unroll
  for (int it = 0; it < 2; ++it) {
    int L = it * 4096 + tid * 16;
    int g = L ^ (((L >> 7) & 7) << 4);
    gload16(khg0 + g, SM + it * 4096 + wave * 1024);
    gload16(klg0 + g, SM + 8192 + it * 4096 + wave * 1024);
  }

  for (int kt = 0; kt < 32; ++kt) {
    __syncthreads();   // stage(kt) landed (issued a full iter ago); buf[kt-1] readers done
    const int cb = (kt & 1) * 16384;
    const int key0 = kt * 64;

    // prefetch V^T A-frags from global (L2): consumed after softmax
    bf16x8 vtf[2][4];
#pragma unroll
    for (int dt = 0; dt < 2; dt++)
#pragma unroll
      for (int s = 0; s < 4; s++)
        vtf[dt][s] = *(const bf16x8*)(vt + base + (l5 + 32 * dt) * NS + key0 + s * 16 + hi * 8);

    if (kt < 31) {   // stage kt+1 into the other buffer; lands during compute
      const int nb2 = ((kt + 1) & 1) * 16384;
      const char* khg = khg0 + (key0 + 64) * 128;
      const char* klg = klg0 + (key0 + 64) * 128;
#pragma unroll
      for (int it = 0; it < 2; ++it) {
        int L = it * 4096 + tid * 16;
        int g = L ^ (((L >> 7) & 7) << 4);
        gload16(khg + g, SM + nb2 + it * 4096 + wave * 1024);
        gload16(klg + g, SM + nb2 + 8192 + it * 4096 + wave * 1024);
      }
    }

    // S^T = K Q^T : 3-term hi/lo, 24 mfma32
    floatx16 sacc[2];
#pragma unroll
    for (int t = 0; t < 2; t++)
#pragma unroll
      for (int r = 0; r < 16; r++) sacc[t][r] = 0.f;
#pragma unroll
    for (int t = 0; t < 2; t++) {
      const int row = 32 * t + l5;
      const int swz = (row & 7) << 4;
#pragma unroll
      for (int s = 0; s < 4; s++) {
        int byt = cb + row * 128 + ((s * 32 + hi * 16) ^ swz);
        bf16x8 ah = *(const bf16x8*)(SM + byt);
        bf16x8 al8 = *(const bf16x8*)(SM + 8192 + byt);
        __builtin_amdgcn_s_setprio(1);
        sacc[t] = __builtin_amdgcn_mfma_f32_32x32x16_bf16(ah, qfh[s], sacc[t], 0, 0, 0);
        sacc[t] = __builtin_amdgcn_mfma_f32_32x32x16_bf16(ah, qfl[s], sacc[t], 0, 0, 0);
        sacc[t] = __builtin_amdgcn_mfma_f32_32x32x16_bf16(al8, qfh[s], sacc[t], 0, 0, 0);
        __builtin_amdgcn_s_setprio(0);
      }
    }

    // ---- in-register online softmax (lane owns q-row = l5) ----------------
    float mt = fmaxf(sacc[0][0], sacc[0][1]);
#pragma unroll
    for (int r = 2; r < 16; r += 2) mt = fmaxf(mt, fmaxf(sacc[0][r], sacc[0][r + 1]));
#pragma unroll
    for (int r = 0; r < 16; r += 2) mt = fmaxf(mt, fmaxf(sacc[1][r], sacc[1][r + 1]));
    mt = mergemax(mt);                        // lane<->lane+32 merge
    if (!__all(mt <= m_r + 8.0f)) {           // defer-max (T13)
      float mn = fmaxf(m_r, mt);
      float sc2 = exp2f(m_r - mn);
      l_r *= sc2;
#pragma unroll
      for (int dt = 0; dt < 2; dt++)
#pragma unroll
        for (int r = 0; r < 16; r++) acco[dt][r] *= sc2;
      m_r = mn;
    }
    float ls = 0.f;
#pragma unroll
    for (int t = 0; t < 2; t++)
#pragma unroll
      for (int r = 0; r < 16; r++) {
        float p = exp2f(sacc[t][r] - m_r);
        sacc[t][r] = p; ls += p;
      }
    l_r += mergesum(ls);

    // ---- pack P (cvt casts -> v_cvt_pk; permlane32_swap exchange), PV -----
#pragma unroll
    for (int s = 0; s < 4; s++) {
      int t = s >> 1, rb = (s & 1) * 8;
      union { __bf16 bb[8]; unsigned u[4]; } Wp;
#pragma unroll
      for (int j = 0; j < 8; j++) Wp.bb[j] = (__bf16)sacc[t][rb + j];
      uint2v r02 = pl32(Wp.u[0], Wp.u[2]);   // {keys01', keys45'}
      uint2v r13 = pl32(Wp.u[1], Wp.u[3]);   // {keys23', keys67'}
      union { unsigned u[4]; bf16x8 v; } P;
      P.u[0] = r02[0]; P.u[1] = r13[0]; P.u[2] = r02[1]; P.u[3] = r13[1];
      __builtin_amdgcn_s_setprio(1);
      acco[0] = __builtin_amdgcn_mfma_f32_32x32x16_bf16(vtf[0][s], P.v, acco[0], 0, 0, 0);
      acco[1] = __builtin_amdgcn_mfma_f32_32x32x16_bf16(vtf[1][s], P.v, acco[1], 0, 0, 0);
      __builtin_amdgcn_s_setprio(0);
    }
  }
  __syncthreads();   // done reading K bufs; SM reused for O transpose

  // ---- O write: XOR-swizzled LDS transpose -> coalesced hi/lo bf16 stores --
  float inv = 1.0f / l_r;
  float* OT = (float*)SM;
#pragma unroll
  for (int dt = 0; dt < 2; dt++)
#pragma unroll
    for (int r = 0; r < 16; r++) {
      int col = (r & 3) + 8 * (r >> 2) + 4 * hi + 32 * dt;  // d
      int cs = (col & 32) | ((col ^ l5) & 31);
      OT[(wave * 32 + l5) * 64 + cs] = acco[dt][r] * inv;
    }
  __syncthreads();
  {
    int row = tid >> 1, h = tid & 1;
    union { u16 s8[8]; ushort8 v; } HB[4], LB[4];
#pragma unroll
    for (int j = 0; j < 32; j++) {
      int c = h * 32 + j;
      int cs = (c & 32) | ((c ^ (row & 31)) & 31);
      float f = OT[row * 64 + cs];
      u16 hb = f2bf(f);
      HB[j >> 3].s8[j & 7] = hb;
      LB[j >> 3].s8[j & 7] = f2bf(f - bf2f(hb));
    }
    size_t doff = ((size_t)(b * NS + qt * 128 + row)) * NHID + hco + h * 32;
#pragma unroll
    for (int q = 0; q < 4; q++) {
      *(ushort8*)(aoh + doff + q * 8) = HB[q].v;
      *(ushort8*)(aol + doff + q * 8) = LB[q].v;
    }
  }
}

__global__ void k_scale(const double* __restrict__ sums, const float* __restrict__ hss,
                        float* __restrict__ out) {
  if (threadIdx.x == 0) {
    float sv = (float)(sums[2] / (double)WELEM) + 1e-5f;
    float so = (float)(sums[3] / (double)WELEM) + 1e-5f;
    out[NTOK * NHID] = hss[0] * sv * so;
  }
}

extern "C" void kernel_launch(void* const* d_in, const int* in_sizes, int n_in,
                              void* d_out, int out_size, void* d_ws, size_t ws_size,
                              hipStream_t stream) {
  const float* x   = (const float*)d_in[0];
  const float* hss = (const float*)d_in[1];
  const int*   pos = (const int*)d_in[2];
  const float* wq  = (const float*)d_in[3];
  const float* wk  = (const float*)d_in[4];
  const float* wv  = (const float*)d_in[5];
  const float* wo  = (const float*)d_in[6];
  float* out = (float*)d_out;
  char* ws = (char*)d_ws;
  const size_t MB = 1u << 20;
  u16* wt = (u16*)(ws);              // 4 ternary matrices, 8MB
  u16* xh = (u16*)(ws + 8 * MB);
  u16* xl = (u16*)(ws + 16 * MB);
  u16* qh = (u16*)(ws + 24 * MB);
  u16* ql = (u16*)(ws + 32 * MB);
  u16* kh = (u16*)(ws + 40 * MB);
  u16* kl = (u16*)(ws + 48 * MB);
  u16* vh = (u16*)(ws + 56 * MB);
  u16* vt = (u16*)(ws + 64 * MB);    // transposed V [bh][d][s]
  double* sums = (double*)(ws + 72 * MB);
  u16* aoh = xh;  // x no longer needed after QKV proj
  u16* aol = xl;

  k_init<<<1, 64, 0, stream>>>(sums);
  k_abssum<<<dim3(256, 4), 256, 0, stream>>>(wq, wk, wv, wo, sums);
  k_quant<<<dim3(1024, 4), 256, 0, stream>>>(wq, wk, wv, wo, sums, wt);
  k_split<<<4096, 256, 0, stream>>>(x, xh, xl);
  k_gemm<0><<<dim3(32, 8, 3), 256, 0, stream>>>(xh, xl, wt, nullptr, qh, ql, kh, kl, vh);
  k_vtrans<<<dim3(32, 32), 256, 0, stream>>>(vh, vt);
  k_rope<<<8192, 256, 0, stream>>>(pos, qh, ql, kh, kl);
  k_attn<<<dim3(16, 32), 256, 0, stream>>>(qh, ql, kh, kl, vt, aoh, aol);
  k_gemm<1><<<dim3(32, 8, 1), 256, 0, stream>>>(aoh, aol, wt, out,
                                                nullptr, nullptr, nullptr, nullptr, nullptr);
  k_scale<<<1, 64, 0, stream>>>(sums, hss, out);
}

// Round 6
// 236.959 us; speedup vs baseline: 1.4627x; 1.0434x over previous
//
#include <hip/hip_runtime.h>
#include <hip/hip_bf16.h>

// BitNetAttention: B=2,S=2048,HID=1024,NH=16,HD=64
#define NB 2
#define NS 2048
#define NHID 1024
#define NHEAD 16
#define NHD 64
#define NTOK (NB*NS)        // 4096
#define WELEM (NHID*NHID)   // 1048576

typedef unsigned short u16;
typedef __attribute__((ext_vector_type(4))) float floatx4;
typedef __attribute__((ext_vector_type(16))) float floatx16;
typedef __attribute__((ext_vector_type(8))) __bf16 bf16x8;
typedef __attribute__((ext_vector_type(8))) unsigned short ushort8;
typedef __attribute__((ext_vector_type(2))) unsigned uint2v;

__device__ __forceinline__ u16 f2bf(float f) {
  union { float f; unsigned u; } a; a.f = f;
  unsigned u = a.u;
  unsigned r = (u + 0x7fffu + ((u >> 16) & 1u)) >> 16;  // RNE
  return (u16)r;
}
__device__ __forceinline__ float bf2f(u16 s) {
  union { unsigned u; float f; } a; a.u = ((unsigned)s) << 16;
  return a.f;
}
__device__ __forceinline__ void gload16(const void* g, void* lds) {
  __builtin_amdgcn_global_load_lds(
      (const __attribute__((address_space(1))) unsigned int*)g,
      (__attribute__((address_space(3))) unsigned int*)lds, 16, 0, 0);
}
// v_permlane32_swap_b32 builtin: vdst[32:63] <-> src[0:31]; returns {vdst', src'}
__device__ __forceinline__ uint2v pl32(unsigned a, unsigned b) {
  return __builtin_amdgcn_permlane32_swap(a, b, false, false);
}
__device__ __forceinline__ float mergemax(float x) {
  uint2v r = pl32(__float_as_uint(x), __float_as_uint(x));
  return fmaxf(__uint_as_float(r[0]), __uint_as_float(r[1]));
}
__device__ __forceinline__ float mergesum(float x) {
  uint2v r = pl32(__float_as_uint(x), __float_as_uint(x));
  return __uint_as_float(r[0]) + __uint_as_float(r[1]);
}

// ---------------- scale reduction (fp64 for boundary fidelity) --------------
__global__ void k_init(double* sums) { if (threadIdx.x < 4) sums[threadIdx.x] = 0.0; }

__global__ void k_abssum(const float* __restrict__ wq, const float* __restrict__ wk,
                         const float* __restrict__ wv, const float* __restrict__ wo,
                         double* __restrict__ sums) {
  const float* srcs[4] = {wq, wk, wv, wo};
  const float* w = srcs[blockIdx.y];
  int idx = (blockIdx.x * 256 + threadIdx.x) * 16;
  float s = 0.f;
#pragma unroll
  for (int j = 0; j < 4; j++) {
    float4 v = *(const float4*)(w + idx + j * 4);
    s += fabsf(v.x) + fabsf(v.y) + fabsf(v.z) + fabsf(v.w);
  }
#pragma unroll
  for (int off = 32; off; off >>= 1) s += __shfl_down(s, off);
  __shared__ float ps[4];
  if ((threadIdx.x & 63) == 0) ps[threadIdx.x >> 6] = s;
  __syncthreads();
  if (threadIdx.x == 0) atomicAdd(&sums[blockIdx.y], (double)(ps[0] + ps[1] + ps[2] + ps[3]));
}

__global__ void k_quant(const float* __restrict__ wq, const float* __restrict__ wk,
                        const float* __restrict__ wv, const float* __restrict__ wo,
                        const double* __restrict__ sums, u16* __restrict__ wt) {
  const float* srcs[4] = {wq, wk, wv, wo};
  const float* w = srcs[blockIdx.y];
  u16* dst = wt + blockIdx.y * WELEM;
  float s = (float)(sums[blockIdx.y] / (double)WELEM) + 1e-5f;
  int idx = (blockIdx.x * 256 + threadIdx.x) * 4;
  float4 v = *(const float4*)(w + idx);
  float f[4] = {v.x, v.y, v.z, v.w};
  union { u16 ss[4]; uint2 u; } O;
#pragma unroll
  for (int j = 0; j < 4; j++) {
    float q = rintf(f[j] / s);            // round-half-even, matches np.round
    q = fminf(1.f, fmaxf(-1.f, q));
    O.ss[j] = f2bf(q);                    // ternary exact in bf16
  }
  *(uint2*)(dst + idx) = O.u;
}

// ---------------- fp32 -> bf16 hi/lo split ---------------------------------
__global__ void k_split(const float* __restrict__ x, u16* __restrict__ hi, u16* __restrict__ lo) {
  int idx = (blockIdx.x * 256 + threadIdx.x) * 4;
  float4 v = *(const float4*)(x + idx);
  float f[4] = {v.x, v.y, v.z, v.w};
  union { u16 s[4]; uint2 u; } H, L;
#pragma unroll
  for (int j = 0; j < 4; j++) {
    u16 hb = f2bf(f[j]);
    H.s[j] = hb;
    L.s[j] = f2bf(f[j] - bf2f(hb));
  }
  *(uint2*)(hi + idx) = H.u;
  *(uint2*)(lo + idx) = L.u;
}

// ---------------- GEMM: C[m,o] = sum_k (Ahi+Alo)[m,k] * W[o,k] --------------
// Double-buffered, one barrier/iter, W staged ONCE per k-tile (shared by
// the hi and lo MFMA terms). LDS: 2 bufs x {Ah,Al,B} x 8KB = 48KB.
template <int MODE>
__global__ __launch_bounds__(256) void k_gemm(
    const u16* __restrict__ Ahi, const u16* __restrict__ Alo,
    const u16* __restrict__ Wt, float* __restrict__ outf,
    u16* __restrict__ qh, u16* __restrict__ ql,
    u16* __restrict__ kh, u16* __restrict__ kl,
    u16* __restrict__ vh) {
  __shared__ __attribute__((aligned(16))) char GSM[49152];
  const int tid = threadIdx.x;
  const int wave = tid >> 6, lane = tid & 63;
  const int lr = lane & 15, lh = lane >> 4;
  const int bm = blockIdx.x, bn = blockIdx.y, z = blockIdx.z;
  const u16* W = Wt + (MODE == 0 ? z : 3) * WELEM;
  const int wr = wave >> 1, wc = wave & 1;

  floatx4 acc[4][4];
#pragma unroll
  for (int i = 0; i < 4; i++)
#pragma unroll
    for (int j = 0; j < 4; j++) acc[i][j] = (floatx4){0.f, 0.f, 0.f, 0.f};

  const int e0 = tid * 8;
  const int row0 = e0 >> 5, col0 = e0 & 31;

  // prologue: stage k-tile 0 into buf 0
#pragma unroll
  for (int it = 0; it < 2; ++it) {
    int row = row0 + it * 64;
    gload16(Ahi + (bm * 128 + row) * 1024 + col0, GSM + it * 4096 + wave * 1024);
    gload16(Alo + (bm * 128 + row) * 1024 + col0, GSM + 8192 + it * 4096 + wave * 1024);
    gload16(W   + (bn * 128 + row) * 1024 + col0, GSM + 16384 + it * 4096 + wave * 1024);
  }

  for (int kt = 0; kt < 32; ++kt) {  // K = 1024, 32-wide tiles
    __syncthreads();                 // stage(kt) complete; buf[kt-1] readers done
    const int cb = (kt & 1) * 24576;
    if (kt < 31) {
      const int nb2 = ((kt + 1) & 1) * 24576;
      const int k0 = (kt + 1) * 32;
#pragma unroll
      for (int it = 0; it < 2; ++it) {
        int row = row0 + it * 64;
        gload16(Ahi + (bm * 128 + row) * 1024 + k0 + col0, GSM + nb2 + it * 4096 + wave * 1024);
        gload16(Alo + (bm * 128 + row) * 1024 + k0 + col0, GSM + nb2 + 8192 + it * 4096 + wave * 1024);
        gload16(W   + (bn * 128 + row) * 1024 + k0 + col0, GSM + nb2 + 16384 + it * 4096 + wave * 1024);
      }
    }
    const u16* Ahp = (const u16*)(GSM + cb);
    const u16* Alp = (const u16*)(GSM + cb + 8192);
    const u16* Bp  = (const u16*)(GSM + cb + 16384);
    bf16x8 ah[4], al8[4], bfr[4];
#pragma unroll
    for (int mi = 0; mi < 4; mi++) {
      ah[mi]  = *(const bf16x8*)(Ahp + (wr * 64 + mi * 16 + lr) * 32 + lh * 8);
      al8[mi] = *(const bf16x8*)(Alp + (wr * 64 + mi * 16 + lr) * 32 + lh * 8);
    }
#pragma unroll
    for (int ni = 0; ni < 4; ni++)
      bfr[ni] = *(const bf16x8*)(Bp + (wc * 64 + ni * 16 + lr) * 32 + lh * 8);
#pragma unroll
    for (int mi = 0; mi < 4; mi++)
#pragma unroll
      for (int ni = 0; ni < 4; ni++) {
        acc[mi][ni] = __builtin_amdgcn_mfma_f32_16x16x32_bf16(ah[mi], bfr[ni], acc[mi][ni], 0, 0, 0);
        acc[mi][ni] = __builtin_amdgcn_mfma_f32_16x16x32_bf16(al8[mi], bfr[ni], acc[mi][ni], 0, 0, 0);
      }
  }

#pragma unroll
  for (int mi = 0; mi < 4; mi++)
#pragma unroll
    for (int ni = 0; ni < 4; ni++)
#pragma unroll
      for (int i = 0; i < 4; i++) {
        int row = bm * 128 + wr * 64 + mi * 16 + lh * 4 + i;  // token
        int col = bn * 128 + wc * 64 + ni * 16 + lr;          // out feature
        float v = acc[mi][ni][i];
        if (MODE == 1) {
          outf[row * 1024 + col] = v;
        } else {
          int b = row >> 11, s = row & 2047, hh = col >> 6, hd = col & 63;
          int dst = ((b * NHEAD + hh) * NS + s) * NHD + hd;
          u16 hb = f2bf(v);
          if (z == 0)      { qh[dst] = hb; ql[dst] = f2bf(v - bf2f(hb)); }
          else if (z == 1) { kh[dst] = hb; kl[dst] = f2bf(v - bf2f(hb)); }
          else             { vh[dst] = hb; }   // V: single bf16
        }
      }
}

// ---------------- V transpose: vh[bh][s][d] -> vt[bh][d][s] ----------------
__global__ void k_vtrans(const u16* __restrict__ vh, u16* __restrict__ vt) {
  const int bh = blockIdx.y;
  const int s0 = blockIdx.x * 64;
  const int t = threadIdx.x;
  const int d = t >> 2, j0 = (t & 3) * 16;
  const u16* src = vh + bh * (NS * NHD) + (s0 + j0) * NHD + d;
  ushort8 a, b;
#pragma unroll
  for (int j = 0; j < 8; j++) a[j] = src[j * NHD];
#pragma unroll
  for (int j = 0; j < 8; j++) b[j] = src[(8 + j) * NHD];
  u16* dst = vt + bh * (NHD * NS) + d * NS + s0 + j0;
  *(ushort8*)dst = a;
  *(ushort8*)(dst + 8) = b;
}

// ---------------- RoPE (in-place on hi/lo pairs) ----------------------------
__global__ void k_rope(const int* __restrict__ pos_ids,
                       u16* __restrict__ qh, u16* __restrict__ ql,
                       u16* __restrict__ kh, u16* __restrict__ kl) {
  int gid = blockIdx.x * 256 + threadIdx.x;
  int row = gid >> 5, d = gid & 31;          // row in [0, B*NH*S)
  int bh = row >> 11, s = row & 2047, b = bh >> 4;
  int pos = pos_ids[b * NS + s];
  // 1/10000^(2d/64) = 2^(-d*log2(10000)/32)
  float inv = exp2f((float)d * -0.4152410118609203f);
  float fr = (float)pos * inv;
  float c = cosf(fr), sn = sinf(fr);   // precise trig: match np reference
  int off = row * 64 + d;
  {
    float x1 = bf2f(qh[off]) + bf2f(ql[off]);
    float x2 = bf2f(qh[off + 32]) + bf2f(ql[off + 32]);
    float n1 = x1 * c - x2 * sn;
    float n2 = x2 * c + x1 * sn;
    u16 h1 = f2bf(n1); qh[off] = h1;       ql[off] = f2bf(n1 - bf2f(h1));
    u16 h2 = f2bf(n2); qh[off + 32] = h2;  ql[off + 32] = f2bf(n2 - bf2f(h2));
  }
  {
    float x1 = bf2f(kh[off]) + bf2f(kl[off]);
    float x2 = bf2f(kh[off + 32]) + bf2f(kl[off + 32]);
    float n1 = x1 * c - x2 * sn;
    float n2 = x2 * c + x1 * sn;
    u16 h1 = f2bf(n1); kh[off] = h1;       kl[off] = f2bf(n1 - bf2f(h1));
    u16 h2 = f2bf(n2); kh[off + 32] = h2;  kl[off + 32] = f2bf(n2 - bf2f(h2));
  }
}

// ---------------- flash attention: swapped-operand 32x32 MFMA ---------------
// Double-buffered K AND V^T tiles in LDS (2 x 24KB), ONE barrier per kt.
// All global->LDS staging via coalesced gload16 with pre-swizzled source.
// Lane owns q-row; softmax in-register; permlane32_swap merges/exchanges.
// XCD-chunked block swizzle: each XCD handles 4 consecutive heads -> K/V
// stay L2-resident per XCD.
__global__ __launch_bounds__(256) void k_attn(
    const u16* __restrict__ qh, const u16* __restrict__ ql,
    const u16* __restrict__ kh, const u16* __restrict__ kl,
    const u16* __restrict__ vt, u16* __restrict__ aoh, u16* __restrict__ aol) {
  __shared__ __attribute__((aligned(16))) char SM[49152];
  const int tid = threadIdx.x, wave = tid >> 6, lane = tid & 63;
  const int l5 = lane & 31, hi = lane >> 5;
  const int bid = blockIdx.x;
  const int swzb = ((bid & 7) << 6) | (bid >> 3);   // XCD-chunked (512 = 8*64)
  const int qt = swzb & 15, bh = swzb >> 4;
  const int b = bh >> 4, hco = (bh & 15) * NHD;
  const int base = bh * (NS * NHD);
  const int qrow = qt * 128 + wave * 32 + l5;
  const float SC = 0.125f * 1.4426950408889634f;  // log2 domain

  // Q B-frags: lane holds Q[qrow][s*16 + hi*8 + j], hi/lo re-split after scale
  bf16x8 qfh[4], qfl[4];
#pragma unroll
  for (int s = 0; s < 4; s++) {
    int off = base + qrow * NHD + s * 16 + hi * 8;
    ushort8 hu = *(const ushort8*)(qh + off);
    ushort8 lu = *(const ushort8*)(ql + off);
    union { ushort8 u; bf16x8 v; } H, L;
#pragma unroll
    for (int j = 0; j < 8; j++) {
      float f = (bf2f(hu[j]) + bf2f(lu[j])) * SC;
      u16 hb = f2bf(f);
      H.u[j] = hb; L.u[j] = f2bf(f - bf2f(hb));
    }
    qfh[s] = H.v; qfl[s] = L.v;
  }

  floatx16 acco[2];
#pragma unroll
  for (int dt = 0; dt < 2; dt++)
#pragma unroll
    for (int r = 0; r < 16; r++) acco[dt][r] = 0.f;
  float m_r = -1e30f, l_r = 0.f;

  const char* khg0 = (const char*)(kh + base);
  const char* klg0 = (const char*)(kl + base);
  const char* vtg0 = (const char*)(vt + base);   // [64 d-rows][NS], row stride 4096B

  // stage tile kt into LDS buffer nb (Kh, Kl, Vt); pre-swizzled sources
#define STAGE_KV(key0_, nb_)                                                     \
  {                                                                              \
    const char* khg = khg0 + (key0_) * 128;                                      \
    const char* klg = klg0 + (key0_) * 128;                                      \
    const char* vtg = vtg0 + (key0_) * 2;                                        \
    _Pragma("unroll")                                                            \
    for (int it = 0; it < 2; ++it) {                                             \
      int L = it * 4096 + tid * 16;                                              \
      int r7 = (L >> 7) & 7;                                                     \
      int g = L ^ (r7 << 4);                                                     \
      gload16(khg + g, SM + (nb_) + it * 4096 + wave * 1024);                    \
      gload16(klg + g, SM + (nb_) + 8192 + it * 4096 + wave * 1024);             \
      int vcol = (L & 127) ^ (r7 << 4);                                          \
      gload16(vtg + (size_t)(L >> 7) * 4096 + vcol,                              \
              SM + (nb_) + 16384 + it * 4096 + wave * 1024);                     \
    }                                                                            \
  }

  // prologue: stage kt=0 into buf 0
  STAGE_KV(0, 0);

  for (int kt = 0; kt < 32; ++kt) {
    __syncthreads();   // stage(kt) landed (issued a full iter ago); buf[kt-1] readers done
    const int cb = (kt & 1) * 24576;
    const int key0 = kt * 64;

    if (kt < 31) {   // stage kt+1 into the other buffer; lands during compute
      const int nb2 = ((kt + 1) & 1) * 24576;
      STAGE_KV(key0 + 64, nb2);
    }

    // S^T = K Q^T : 3-term hi/lo, 24 mfma32
    floatx16 sacc[2];
#pragma unroll
    for (int t = 0; t < 2; t++)
#pragma unroll
      for (int r = 0; r < 16; r++) sacc[t][r] = 0.f;
#pragma unroll
    for (int t = 0; t < 2; t++) {
      const int row = 32 * t + l5;
      const int swz = (row & 7) << 4;
#pragma unroll
      for (int s = 0; s < 4; s++) {
        int byt = cb + row * 128 + ((s * 32 + hi * 16) ^ swz);
        bf16x8 ah = *(const bf16x8*)(SM + byt);
        bf16x8 al8 = *(const bf16x8*)(SM + 8192 + byt);
        __builtin_amdgcn_s_setprio(1);
        sacc[t] = __builtin_amdgcn_mfma_f32_32x32x16_bf16(ah, qfh[s], sacc[t], 0, 0, 0);
        sacc[t] = __builtin_amdgcn_mfma_f32_32x32x16_bf16(ah, qfl[s], sacc[t], 0, 0, 0);
        sacc[t] = __builtin_amdgcn_mfma_f32_32x32x16_bf16(al8, qfh[s], sacc[t], 0, 0, 0);
        __builtin_amdgcn_s_setprio(0);
      }
    }

    // ---- in-register online softmax (lane owns q-row = l5) ----------------
    float mt = fmaxf(sacc[0][0], sacc[0][1]);
#pragma unroll
    for (int r = 2; r < 16; r += 2) mt = fmaxf(mt, fmaxf(sacc[0][r], sacc[0][r + 1]));
#pragma unroll
    for (int r = 0; r < 16; r += 2) mt = fmaxf(mt, fmaxf(sacc[1][r], sacc[1][r + 1]));
    mt = mergemax(mt);                        // lane<->lane+32 merge
    if (!__all(mt <= m_r + 8.0f)) {           // defer-max (T13)
      float mn = fmaxf(m_r, mt);
      float sc2 = exp2f(m_r - mn);
      l_r *= sc2;
#pragma unroll
      for (int dt = 0; dt < 2; dt++)
#pragma unroll
        for (int r = 0; r < 16; r++) acco[dt][r] *= sc2;
      m_r = mn;
    }
    float ls = 0.f;
#pragma unroll
    for (int t = 0; t < 2; t++)
#pragma unroll
      for (int r = 0; r < 16; r++) {
        float p = exp2f(sacc[t][r] - m_r);
        sacc[t][r] = p; ls += p;
      }
    l_r += mergesum(ls);

    // ---- V^T A-frags from LDS (swizzled ds_read_b128) ---------------------
    bf16x8 vtf[2][4];
#pragma unroll
    for (int dt = 0; dt < 2; dt++) {
      const int vrow = l5 + 32 * dt;
      const int swzv = (vrow & 7) << 4;
#pragma unroll
      for (int s = 0; s < 4; s++)
        vtf[dt][s] = *(const bf16x8*)(SM + cb + 16384 + vrow * 128 + ((s * 32 + hi * 16) ^ swzv));
    }

    // ---- pack P (cvt casts -> v_cvt_pk; permlane32_swap exchange), PV -----
#pragma unroll
    for (int s = 0; s < 4; s++) {
      int t = s >> 1, rb = (s & 1) * 8;
      union { __bf16 bb[8]; unsigned u[4]; } Wp;
#pragma unroll
      for (int j = 0; j < 8; j++) Wp.bb[j] = (__bf16)sacc[t][rb + j];
      uint2v r02 = pl32(Wp.u[0], Wp.u[2]);   // {keys01', keys45'}
      uint2v r13 = pl32(Wp.u[1], Wp.u[3]);   // {keys23', keys67'}
      union { unsigned u[4]; bf16x8 v; } P;
      P.u[0] = r02[0]; P.u[1] = r13[0]; P.u[2] = r02[1]; P.u[3] = r13[1];
      __builtin_amdgcn_s_setprio(1);
      acco[0] = __builtin_amdgcn_mfma_f32_32x32x16_bf16(vtf[0][s], P.v, acco[0], 0, 0, 0);
      acco[1] = __builtin_amdgcn_mfma_f32_32x32x16_bf16(vtf[1][s], P.v, acco[1], 0, 0, 0);
      __builtin_amdgcn_s_setprio(0);
    }
  }
  __syncthreads();   // done reading K/V bufs; SM reused for O transpose

  // ---- O write: XOR-swizzled LDS transpose -> coalesced hi/lo bf16 stores --
  float inv = 1.0f / l_r;
  float* OT = (float*)SM;
#pragma unroll
  for (int dt = 0; dt < 2; dt++)
#pragma unroll
    for (int r = 0; r < 16; r++) {
      int col = (r & 3) + 8 * (r >> 2) + 4 * hi + 32 * dt;  // d
      int cs = (col & 32) | ((col ^ l5) & 31);
      OT[(wave * 32 + l5) * 64 + cs] = acco[dt][r] * inv;
    }
  __syncthreads();
  {
    int row = tid >> 1, h = tid & 1;
    union { u16 s8[8]; ushort8 v; } HB[4], LB[4];
#pragma unroll
    for (int j = 0; j < 32; j++) {
      int c = h * 32 + j;
      int cs = (c & 32) | ((c ^ (row & 31)) & 31);
      float f = OT[row * 64 + cs];
      u16 hb = f2bf(f);
      HB[j >> 3].s8[j & 7] = hb;
      LB[j >> 3].s8[j & 7] = f2bf(f - bf2f(hb));
    }
    size_t doff = ((size_t)(b * NS + qt * 128 + row)) * NHID + hco + h * 32;
#pragma unroll
    for (int q = 0; q < 4; q++) {
      *(ushort8*)(aoh + doff + q * 8) = HB[q].v;
      *(ushort8*)(aol + doff + q * 8) = LB[q].v;
    }
  }
}

__global__ void k_scale(const double* __restrict__ sums, const float* __restrict__ hss,
                        float* __restrict__ out) {
  if (threadIdx.x == 0) {
    float sv = (float)(sums[2] / (double)WELEM) + 1e-5f;
    float so = (float)(sums[3] / (double)WELEM) + 1e-5f;
    out[NTOK * NHID] = hss[0] * sv * so;
  }
}

extern "C" void kernel_launch(void* const* d_in, const int* in_sizes, int n_in,
                              void* d_out, int out_size, void* d_ws, size_t ws_size,
                              hipStream_t stream) {
  const float* x   = (const float*)d_in[0];
  const float* hss = (const float*)d_in[1];
  const int*   pos = (const int*)d_in[2];
  const float* wq  = (const float*)d_in[3];
  const float* wk  = (const float*)d_in[4];
  const float* wv  = (const float*)d_in[5];
  const float* wo  = (const float*)d_in[6];
  float* out = (float*)d_out;
  char* ws = (char*)d_ws;
  const size_t MB = 1u << 20;
  u16* wt = (u16*)(ws);              // 4 ternary matrices, 8MB
  u16* xh = (u16*)(ws + 8 * MB);
  u16* xl = (u16*)(ws + 16 * MB);
  u16* qh = (u16*)(ws + 24 * MB);
  u16* ql = (u16*)(ws + 32 * MB);
  u16* kh = (u16*)(ws + 40 * MB);
  u16* kl = (u16*)(ws + 48 * MB);
  u16* vh = (u16*)(ws + 56 * MB);
  u16* vt = (u16*)(ws + 64 * MB);    // transposed V [bh][d][s]
  double* sums = (double*)(ws + 72 * MB);
  u16* aoh = xh;  // x no longer needed after QKV proj
  u16* aol = xl;

  k_init<<<1, 64, 0, stream>>>(sums);
  k_abssum<<<dim3(256, 4), 256, 0, stream>>>(wq, wk, wv, wo, sums);
  k_quant<<<dim3(1024, 4), 256, 0, stream>>>(wq, wk, wv, wo, sums, wt);
  k_split<<<4096, 256, 0, stream>>>(x, xh, xl);
  k_gemm<0><<<dim3(32, 8, 3), 256, 0, stream>>>(xh, xl, wt, nullptr, qh, ql, kh, kl, vh);
  k_vtrans<<<dim3(32, 32), 256, 0, stream>>>(vh, vt);
  k_rope<<<8192, 256, 0, stream>>>(pos, qh, ql, kh, kl);
  k_attn<<<512, 256, 0, stream>>>(qh, ql, kh, kl, vt, aoh, aol);
  k_gemm<1><<<dim3(32, 8, 1), 256, 0, stream>>>(aoh, aol, wt, out,
                                                nullptr, nullptr, nullptr, nullptr, nullptr);
  k_scale<<<1, 64, 0, stream>>>(sums, hss, out);
}